// Round 5
// baseline (313.360 us; speedup 1.0000x reference)
//
#include <hip/hip_runtime.h>
#include <hip/hip_bf16.h>
#include <hip/hip_fp16.h>
#include <math.h>

// Problem dims
#define B 64
#define S 2048
#define E 512
#define HD 512
#define TD 128
#define M_TOT (B*S)

// Workspace layout (in floats)
#define OFF_MASK   0                        // B*S
#define OFF_CTXP   (OFF_MASK + B*S)         // 8*B*E
#define OFF_LENP   (OFF_CTXP + 8*B*E)       // 8*B
#define OFF_CB     (OFF_LENP + 8*B)         // B*HD
#define OFF_REPP   (OFF_CB + B*HD)          // 8*B*E
#define OFF_SCP    (OFF_REPP + 8*B*E)       // 2*B*S score partials
#define OFF_WPK    (OFF_SCP + 2*B*S)        // 262144 fp16 = 131072 floats (W packed)
#define OFF_WH     (OFF_WPK + 131072)       // words fp16: B*S*E shorts = 33554432 floats
#define WS_NEED_FLOATS ((size_t)OFF_WH + (size_t)B*S*E/2)

typedef __attribute__((ext_vector_type(8))) short short8;
typedef __attribute__((ext_vector_type(4))) float f32x4;
typedef __attribute__((ext_vector_type(4))) unsigned short ushort4_t;

__device__ inline unsigned int f2hu(float x) {
    __half h = __float2half(x);
    unsigned short u; __builtin_memcpy(&u, &h, 2); return (unsigned int)u;
}
__device__ inline float hu2f(unsigned short u) {
    __half h; __builtin_memcpy(&h, &u, 2); return __half2float(h);
}

// fast tanh: exact saturation, ~1e-6 rel err, no NaN (e in (0,1])
__device__ inline float fast_tanh(float x) {
    float a = fabsf(x);
    float e = __expf(-2.0f * a);
    float r = (1.0f - e) / (1.0f + e);
    return copysignf(r, x);
}

// ---------------------------------------------------------------------------
// k0: pack top half of W_att into MFMA B-fragment layout, fp16.
// lane l holds B[k=(l>>4)*8+j][col=l&15]
// ---------------------------------------------------------------------------
__global__ __launch_bounds__(256)
void k0_pack(const float* __restrict__ W_att, unsigned short* __restrict__ Wpk)
{
    int tid = blockIdx.x*256 + threadIdx.x;   // 262144 total
    int e = tid >> 9, h = tid & 511;
    float w = W_att[(size_t)e*HD + h];
    int kstep = e >> 5, kb = (e >> 3) & 3, j = e & 7, f = h >> 4, l15 = h & 15;
    size_t dst = ((((size_t)kstep*32 + f)*64) + kb*16 + l15)*8 + j;
    Wpk[dst] = (unsigned short)f2hu(w);
}

// ---------------------------------------------------------------------------
// K1: mask, column partial sums, lengths; optionally write fp16 words copy
// ---------------------------------------------------------------------------
template<bool WRITE_H>
__global__ __launch_bounds__(256)
void k1_maskcol(const float* __restrict__ words, float* __restrict__ mask,
                float* __restrict__ ctxp, float* __restrict__ lenp,
                unsigned short* __restrict__ wordsH)
{
    int bid = blockIdx.x;            // 512 = B * 8
    int b = bid >> 3, ch = bid & 7;
    int t = threadIdx.x;
    int w = t >> 6, l = t & 63;
    __shared__ __align__(16) float colred[4][E];
    __shared__ float lenred[4];
    const float* base = words + (size_t)(b * S + ch * 256) * E;
    unsigned short* hbase = wordsH + (size_t)(b * S + ch * 256) * E;
    float4 c0 = make_float4(0.f,0.f,0.f,0.f), c1 = make_float4(0.f,0.f,0.f,0.f);
    float wlen = 0.0f;
    for (int r = w; r < 256; r += 4) {
        const float* row = base + (size_t)r * E;
        float4 a  = *(const float4*)(row + 4*l);
        float4 bb = *(const float4*)(row + 256 + 4*l);
        if (WRITE_H) {
            ushort4_t ha, hb;
            ha[0]=(unsigned short)f2hu(a.x);  ha[1]=(unsigned short)f2hu(a.y);
            ha[2]=(unsigned short)f2hu(a.z);  ha[3]=(unsigned short)f2hu(a.w);
            hb[0]=(unsigned short)f2hu(bb.x); hb[1]=(unsigned short)f2hu(bb.y);
            hb[2]=(unsigned short)f2hu(bb.z); hb[3]=(unsigned short)f2hu(bb.w);
            *(ushort4_t*)(hbase + (size_t)r*E + 4*l)       = ha;
            *(ushort4_t*)(hbase + (size_t)r*E + 256 + 4*l) = hb;
        }
        float rs = a.x+a.y+a.z+a.w + bb.x+bb.y+bb.z+bb.w;
        #pragma unroll
        for (int m = 1; m < 64; m <<= 1) rs += __shfl_xor(rs, m);
        c0.x += a.x;  c0.y += a.y;  c0.z += a.z;  c0.w += a.w;
        c1.x += bb.x; c1.y += bb.y; c1.z += bb.z; c1.w += bb.w;
        if (l == 0) {
            float mv = (rs != 0.0f) ? 1.0f : 0.0f;
            mask[(size_t)b*S + ch*256 + r] = mv;
            wlen += mv;
        }
    }
    *(float4*)&colred[w][4*l]       = c0;
    *(float4*)&colred[w][256 + 4*l] = c1;
    if (l == 0) lenred[w] = wlen;
    __syncthreads();
    float s1 = colred[0][t]+colred[1][t]+colred[2][t]+colred[3][t];
    float s2 = colred[0][t+256]+colred[1][t+256]+colred[2][t+256]+colred[3][t+256];
    size_t o = ((size_t)ch * B + b) * E;
    ctxp[o + t]       = s1;
    ctxp[o + t + 256] = s2;
    if (t == 0) lenp[ch*B + b] = lenred[0]+lenred[1]+lenred[2]+lenred[3];
}

// ---------------------------------------------------------------------------
// K2: cb[b,h] = b_att[h] + context_b . W_att[E:, h]
// ---------------------------------------------------------------------------
__global__ __launch_bounds__(256)
void k2_cb(const float* __restrict__ W_att, const float* __restrict__ b_att,
           const float* __restrict__ ctxp, const float* __restrict__ lenp,
           float* __restrict__ cb)
{
    int bid = blockIdx.x;            // 128
    int b = bid >> 1, hc = bid & 1;
    int t = threadIdx.x;
    __shared__ float ctxL[E];
    float len = 0.f;
    #pragma unroll
    for (int k = 0; k < 8; ++k) len += lenp[k*B + b];
    float inv = 1.0f / len;
    for (int c = t; c < E; c += 256) {
        float sv = 0.f;
        #pragma unroll
        for (int k = 0; k < 8; ++k) sv += ctxp[((size_t)k*B + b)*E + c];
        ctxL[c] = sv * inv;
    }
    __syncthreads();
    int h = hc*256 + t;
    const float* Wb = W_att + (size_t)E * HD;
    float a0 = b_att[h], a1 = 0.f, a2 = 0.f, a3 = 0.f;
    #pragma unroll 4
    for (int e = 0; e < E; e += 4) {
        a0 += ctxL[e]   * Wb[(size_t)e*HD + h];
        a1 += ctxL[e+1] * Wb[(size_t)(e+1)*HD + h];
        a2 += ctxL[e+2] * Wb[(size_t)(e+2)*HD + h];
        a3 += ctxL[e+3] * Wb[(size_t)(e+3)*HD + h];
    }
    cb[(size_t)b*HD + h] = (a0 + a1) + (a2 + a3);
}

// ---------------------------------------------------------------------------
// K3: fp16 MFMA scores. Block tile 128(M) x 256(N per nc), BK=32, 8 waves
// (2 wr x 4 wc), wave = 64x64. A: LDS dbuf 2x8KB frag-packed; F16 path reads
// the pre-converted fp16 copy (1 x 16B load + 1 x 16B ds_write, no cvt).
// B: direct global->reg from packed Wpk (L2-resident), reload after last use.
// ---------------------------------------------------------------------------
template<bool F16>
__global__ __launch_bounds__(512, 4)
void k3_scores(const float* __restrict__ words,
               const unsigned short* __restrict__ wordsH,
               const unsigned short* __restrict__ Wpk,
               const float* __restrict__ cb, const float* __restrict__ v,
               float* __restrict__ scp)
{
    __shared__ __align__(16) unsigned char smem[16384];   // A dbuf: 2 x 8KB
    int bid = blockIdx.x;             // 2048 = 1024 mtiles * 2 nchunks
    int mt = bid >> 1, nc = bid & 1;
    int m0 = mt * 128;
    int b  = m0 >> 11;                // S = 2048
    int t = threadIdx.x;
    int lane = t & 63, wid = t >> 6;
    int wr = wid >> 2, wc = wid & 3;  // 2 row-groups x 4 col-groups

    f32x4 acc[4][4];
    #pragma unroll
    for (int i = 0; i < 4; ++i)
        #pragma unroll
        for (int j = 0; j < 4; ++j) acc[i][j] = (f32x4)0.0f;

    // ---- A staging: thread t -> row r = t>>2 (4 threads/row), k-quarter kq = t&3
    int r = t >> 2, kq = t & 3;
    const float* aSrcF = words + (size_t)(m0 + r)*E + kq*8;
    const unsigned short* aSrcH = wordsH + (size_t)(m0 + r)*E + kq*8;
    int abase = (r >> 4)*1024 + kq*256 + (r & 15)*16;

    float4 pF[2];
    uint4  pH;

    auto LOADA = [&](int ks) {
        if constexpr (F16) {
            pH = *(const uint4*)(aSrcH + ks*32);
        } else {
            const float* _s = aSrcF + ks*32;
            pF[0] = *(const float4*)(_s); pF[1] = *(const float4*)(_s+4);
        }
    };
    auto STAGEA = [&](unsigned char* buf) {
        if constexpr (F16) {
            *(uint4*)&buf[abase] = pH;
        } else {
            float xs[8] = {pF[0].x,pF[0].y,pF[0].z,pF[0].w, pF[1].x,pF[1].y,pF[1].z,pF[1].w};
            unsigned int uw[4];
            #pragma unroll
            for (int p = 0; p < 4; ++p)
                uw[p] = f2hu(xs[2*p]) | (f2hu(xs[2*p+1]) << 16);
            *(uint4*)&buf[abase] = make_uint4(uw[0],uw[1],uw[2],uw[3]);
        }
    };

    // ---- B fragment base: frag fl = nc*16 + wc*4 + cf
    const unsigned short* bBase = Wpk + (((size_t)(nc*16 + wc*4))*64 + lane)*8;
#define LDB(ks,cf) (*(const short8*)(bBase + ((size_t)(ks)*32 + (cf))*512))

    // ---- prologue
    LOADA(0);
    STAGEA(smem);            // buf0 <- kstep 0
    LOADA(1);                // regs <- kstep 1
    short8 bcur[4];
    #pragma unroll
    for (int cf = 0; cf < 4; ++cf) bcur[cf] = LDB(0, cf);
    __syncthreads();

    for (int k = 0; k < 16; ++k) {
        unsigned char* bufc = smem + (k & 1)*8192;
        unsigned char* bufn = smem + ((k & 1) ^ 1)*8192;

        short8 ah[4];
        #pragma unroll
        for (int rf = 0; rf < 4; ++rf)
            ah[rf] = *(const short8*)&bufc[(wr*4 + rf)*1024 + lane*16];

        if (k < 15) STAGEA(bufn);
        if (k < 14) LOADA(k + 2);

        #pragma unroll
        for (int cf = 0; cf < 4; ++cf) {
            #pragma unroll
            for (int rf = 0; rf < 4; ++rf)
                acc[rf][cf] = __builtin_amdgcn_mfma_f32_16x16x32_f16(ah[rf], bcur[cf], acc[rf][cf], 0, 0, 0);
            if (k < 15) bcur[cf] = LDB(k + 1, cf);
        }
        __syncthreads();
    }

    // ---- epilogue: tanh(+cb)*v, reduce over cols
    float ssum[4][4];
    #pragma unroll
    for (int i = 0; i < 4; ++i)
        #pragma unroll
        for (int rr = 0; rr < 4; ++rr) ssum[i][rr] = 0.f;

    #pragma unroll
    for (int cf = 0; cf < 4; ++cf) {
        int col = nc*256 + wc*64 + cf*16 + (lane & 15);
        float cbv = cb[(size_t)b*HD + col];
        float vv  = v[col];
        #pragma unroll
        for (int rf = 0; rf < 4; ++rf)
            #pragma unroll
            for (int rr = 0; rr < 4; ++rr)
                ssum[rf][rr] += fast_tanh(acc[rf][cf][rr] + cbv) * vv;
    }
    #pragma unroll
    for (int m = 1; m < 16; m <<= 1)
        #pragma unroll
        for (int rf = 0; rf < 4; ++rf)
            #pragma unroll
            for (int rr = 0; rr < 4; ++rr)
                ssum[rf][rr] += __shfl_xor(ssum[rf][rr], m);

    float* scr = (float*)smem;   // reuse LDS; loop ended with barrier
    if ((lane & 15) == 0) {
        #pragma unroll
        for (int rf = 0; rf < 4; ++rf)
            #pragma unroll
            for (int rr = 0; rr < 4; ++rr)
                scr[wc*128 + wr*64 + rf*16 + (lane >> 4)*4 + rr] = ssum[rf][rr];
    }
    __syncthreads();
    if (t < 128) {
        float val = (scr[t] + scr[128 + t]) + (scr[256 + t] + scr[384 + t]);
        scp[(size_t)nc*M_TOT + m0 + t] = val;
    }
#undef LDB
}

// ---------------------------------------------------------------------------
// K4 (fused softstats + rep): block (b, ch). Recompute batch softmax stats
// from scp (16KB L2 reads, redundant x8 but cheap), then weighted col-sum of
// this chunk's 256 rows.
// ---------------------------------------------------------------------------
template<bool F16>
__global__ __launch_bounds__(256)
void k4_rep(const float* __restrict__ words, const unsigned short* __restrict__ wordsH,
            const float* __restrict__ scp, const float* __restrict__ mask,
            float* __restrict__ repp)
{
    int bid = blockIdx.x;            // 512
    int b = bid >> 3, ch = bid & 7;
    int t = threadIdx.x;
    __shared__ float red[256];
    __shared__ float wrow[256];

    float xs[8];
    float mx = -1e30f;
    #pragma unroll
    for (int k = 0; k < 8; ++k) {
        size_t m = (size_t)b*S + 256*k + t;
        float x = scp[m] + scp[(size_t)M_TOT + m];
        x = (mask[m] > 0.0f) ? x : -1e30f;
        xs[k] = x; mx = fmaxf(mx, x);
    }
    red[t] = mx; __syncthreads();
    for (int off = 128; off > 0; off >>= 1) {
        if (t < off) red[t] = fmaxf(red[t], red[t+off]);
        __syncthreads();
    }
    float gmax = red[0]; __syncthreads();
    float se = 0.f;
    #pragma unroll
    for (int k = 0; k < 8; ++k) se += expf(xs[k] - gmax);
    red[t] = se; __syncthreads();
    for (int off = 128; off > 0; off >>= 1) {
        if (t < off) red[t] += red[t+off];
        __syncthreads();
    }
    float den = red[0];
    wrow[t] = expf(xs[ch] - gmax) / den;    // this chunk's row weight
    __syncthreads();

    float2 acc = make_float2(0.f, 0.f);
    if (F16) {
        const unsigned short* base = wordsH + (size_t)(b*S + ch*256)*E + 2*t;
        #pragma unroll 4
        for (int rr = 0; rr < 256; ++rr) {
            unsigned int u = *(const unsigned int*)(base + (size_t)rr*E);
            float a = wrow[rr];
            acc.x = fmaf(a, hu2f((unsigned short)(u & 0xffff)), acc.x);
            acc.y = fmaf(a, hu2f((unsigned short)(u >> 16)),    acc.y);
        }
    } else {
        const float* base = words + (size_t)(b*S + ch*256)*E + 2*t;
        #pragma unroll 4
        for (int rr = 0; rr < 256; ++rr) {
            float2 wv = *(const float2*)(base + (size_t)rr*E);
            float a = wrow[rr];
            acc.x = fmaf(a, wv.x, acc.x);
            acc.y = fmaf(a, wv.y, acc.y);
        }
    }
    size_t o = ((size_t)ch*B + b)*E + 2*t;
    *(float2*)&repp[o] = acc;
}

// ---------------------------------------------------------------------------
// K5 (fused MLP): one block per batch. LDS ping-pong between layers.
// ---------------------------------------------------------------------------
__global__ __launch_bounds__(256)
void k5_mlp(const float* __restrict__ repp,
            const float* __restrict__ W1, const float* __restrict__ b1,
            const float* __restrict__ W2, const float* __restrict__ b2,
            const float* __restrict__ W3, const float* __restrict__ b3,
            float* __restrict__ out)
{
    int b = blockIdx.x;              // 64
    int t = threadIdx.x;             // 256
    __shared__ float xL[HD];
    __shared__ float yL[HD];
    for (int c = t; c < E; c += 256) {
        float sv = 0.f;
        #pragma unroll
        for (int k = 0; k < 8; ++k) sv += repp[((size_t)k*B + b)*E + c];
        xL[c] = sv;
    }
    __syncthreads();
    // layer 1: 512 outputs, 2 per thread
    #pragma unroll
    for (int oo = 0; oo < 2; ++oo) {
        int h = oo*256 + t;
        float a0 = b1[h], a1 = 0.f, a2 = 0.f, a3 = 0.f;
        #pragma unroll 4
        for (int e = 0; e < E; e += 4) {
            a0 += xL[e]   * W1[(size_t)e*HD + h];
            a1 += xL[e+1] * W1[(size_t)(e+1)*HD + h];
            a2 += xL[e+2] * W1[(size_t)(e+2)*HD + h];
            a3 += xL[e+3] * W1[(size_t)(e+3)*HD + h];
        }
        yL[h] = fmaxf((a0 + a1) + (a2 + a3), 0.f);
    }
    __syncthreads();
    // layer 2: 512 outputs, 2 per thread (yL -> xL)
    float l2v[2];
    #pragma unroll
    for (int oo = 0; oo < 2; ++oo) {
        int h = oo*256 + t;
        float a0 = b2[h], a1 = 0.f, a2 = 0.f, a3 = 0.f;
        #pragma unroll 4
        for (int e = 0; e < HD; e += 4) {
            a0 += yL[e]   * W2[(size_t)e*HD + h];
            a1 += yL[e+1] * W2[(size_t)(e+1)*HD + h];
            a2 += yL[e+2] * W2[(size_t)(e+2)*HD + h];
            a3 += yL[e+3] * W2[(size_t)(e+3)*HD + h];
        }
        l2v[oo] = fmaxf((a0 + a1) + (a2 + a3), 0.f);
    }
    __syncthreads();   // all yL reads done
    xL[t] = l2v[0]; xL[256 + t] = l2v[1];
    __syncthreads();
    // layer 3: 128 outputs
    if (t < TD) {
        float a0 = b3[t], a1 = 0.f, a2 = 0.f, a3 = 0.f;
        #pragma unroll 4
        for (int e = 0; e < HD; e += 4) {
            a0 += xL[e]   * W3[(size_t)e*TD + t];
            a1 += xL[e+1] * W3[(size_t)(e+1)*TD + t];
            a2 += xL[e+2] * W3[(size_t)(e+2)*TD + t];
            a3 += xL[e+3] * W3[(size_t)(e+3)*TD + t];
        }
        out[(size_t)b*TD + t] = (a0 + a1) + (a2 + a3);
    }
}

extern "C" void kernel_launch(void* const* d_in, const int* in_sizes, int n_in,
                              void* d_out, int out_size, void* d_ws, size_t ws_size,
                              hipStream_t stream)
{
    const float* words = (const float*)d_in[0];
    const float* W_att = (const float*)d_in[1];
    const float* b_att = (const float*)d_in[2];
    const float* v     = (const float*)d_in[3];
    const float* W1    = (const float*)d_in[4];
    const float* b1    = (const float*)d_in[5];
    const float* W2    = (const float*)d_in[6];
    const float* b2    = (const float*)d_in[7];
    const float* W3    = (const float*)d_in[8];
    const float* b3    = (const float*)d_in[9];
    (void)in_sizes; (void)n_in; (void)out_size;

    float* ws   = (float*)d_ws;
    float* mask = ws + OFF_MASK;
    float* ctxp = ws + OFF_CTXP;
    float* lenp = ws + OFF_LENP;
    float* cb   = ws + OFF_CB;
    float* repp = ws + OFF_REPP;
    float* scp  = ws + OFF_SCP;
    unsigned short* Wpk    = (unsigned short*)(ws + OFF_WPK);
    unsigned short* wordsH = (unsigned short*)(ws + OFF_WH);
    float* out  = (float*)d_out;

    bool useF16 = ws_size >= WS_NEED_FLOATS * sizeof(float);

    hipLaunchKernelGGL(k0_pack, dim3(1024), dim3(256), 0, stream, W_att, Wpk);
    if (useF16) {
        hipLaunchKernelGGL(k1_maskcol<true>,  dim3(B*8), dim3(256), 0, stream, words, mask, ctxp, lenp, wordsH);
    } else {
        hipLaunchKernelGGL(k1_maskcol<false>, dim3(B*8), dim3(256), 0, stream, words, mask, ctxp, lenp, wordsH);
    }
    hipLaunchKernelGGL(k2_cb, dim3(B*2), dim3(256), 0, stream, W_att, b_att, ctxp, lenp, cb);
    if (useF16) {
        hipLaunchKernelGGL(k3_scores<true>,  dim3(2048), dim3(512), 0, stream, words, wordsH, Wpk, cb, v, scp);
        hipLaunchKernelGGL(k4_rep<true>,     dim3(B*8),  dim3(256), 0, stream, words, wordsH, scp, mask, repp);
    } else {
        hipLaunchKernelGGL(k3_scores<false>, dim3(2048), dim3(512), 0, stream, words, wordsH, Wpk, cb, v, scp);
        hipLaunchKernelGGL(k4_rep<false>,    dim3(B*8),  dim3(256), 0, stream, words, wordsH, scp, mask, repp);
    }
    hipLaunchKernelGGL(k5_mlp, dim3(B), dim3(256), 0, stream, repp, W1, b1, W2, b2, W3, b3, out);
}